// Round 9
// baseline (196.758 us; speedup 1.0000x reference)
//
#include <hip/hip_runtime.h>

#define HW_  16384   // H*W = 128*128
#define NPX  32768   // B*H*W

__device__ __forceinline__ float prelu_(float x, float a) { return x >= 0.f ? x : a * x; }

// ---------------- K1: x1 = prelu(conv1x1(x, w1, b1), a1) ----------------
// LDS-slab GEMM: block = 128 px x 32 outs (2 splits). Thread = 2-px pair x 8
// outs with out-group = wave id -> weight ds_reads are wave-uniform broadcasts.
__global__ __launch_bounds__(256, 2) void k_conv1(const float* __restrict__ x,
        const float* __restrict__ w1, const float* __restrict__ b1,
        const float* __restrict__ a1p, float* __restrict__ x1) {
    __shared__ float xs[64 * 128];     // 32 KB: [ch-half][px]
    __shared__ float wT[128 * 36];     // 18 KB: [c][o] stride 36
    int split = blockIdx.x >> 8;       // 0..1, block-uniform
    int tile = blockIdx.x & 255;
    int b = tile >> 7;
    int hw0 = (tile & 127) << 7;       // 128 px per block
    int o0 = split * 32;

    for (int e = threadIdx.x; e < 4096; e += 256) {      // coalesced w1 read
        int o = e >> 7, c = e & 127;
        wT[c * 36 + o] = w1[(o0 + o) * 128 + c];
    }
    int pr = threadIdx.x & 63;         // px-pair 0..63 (128 px)
    int og = threadIdx.x >> 6;         // 0..3, wave-uniform -> outs o0+og*8..+7
    const float a1 = a1p[0];
    float2 acc[8];
    #pragma unroll
    for (int u = 0; u < 8; ++u) { float bv = b1[o0 + og * 8 + u]; acc[u] = make_float2(bv, bv); }
    const float4* xb = (const float4*)(x + (b << 21) + hw0);   // ch stride 4096 f4
    #pragma unroll 1
    for (int half = 0; half < 2; ++half) {
        float4 xv[8];
        #pragma unroll
        for (int i = 0; i < 8; ++i) {
            int e = threadIdx.x + i * 256;               // e = ch*32 + pq
            xv[i] = xb[((half * 64 + (e >> 5)) << 12) + (e & 31)];
        }
        __syncthreads();               // protect xs from previous iteration readers
        #pragma unroll
        for (int i = 0; i < 8; ++i) {
            int e = threadIdx.x + i * 256;
            *(float4*)&xs[(e >> 5) * 128 + (e & 31) * 4] = xv[i];
        }
        __syncthreads();
        #pragma unroll 8
        for (int c2 = 0; c2 < 64; ++c2) {
            float2 tap = *(const float2*)&xs[c2 * 128 + pr * 2];
            const float* wb = &wT[(half * 64 + c2) * 36 + og * 8];
            float4 wva = *(const float4*)wb;             // broadcast (wave-uniform)
            float4 wvb = *(const float4*)(wb + 4);
            acc[0].x = fmaf(wva.x, tap.x, acc[0].x); acc[0].y = fmaf(wva.x, tap.y, acc[0].y);
            acc[1].x = fmaf(wva.y, tap.x, acc[1].x); acc[1].y = fmaf(wva.y, tap.y, acc[1].y);
            acc[2].x = fmaf(wva.z, tap.x, acc[2].x); acc[2].y = fmaf(wva.z, tap.y, acc[2].y);
            acc[3].x = fmaf(wva.w, tap.x, acc[3].x); acc[3].y = fmaf(wva.w, tap.y, acc[3].y);
            acc[4].x = fmaf(wvb.x, tap.x, acc[4].x); acc[4].y = fmaf(wvb.x, tap.y, acc[4].y);
            acc[5].x = fmaf(wvb.y, tap.x, acc[5].x); acc[5].y = fmaf(wvb.y, tap.y, acc[5].y);
            acc[6].x = fmaf(wvb.z, tap.x, acc[6].x); acc[6].y = fmaf(wvb.z, tap.y, acc[6].y);
            acc[7].x = fmaf(wvb.w, tap.x, acc[7].x); acc[7].y = fmaf(wvb.w, tap.y, acc[7].y);
        }
    }
    #pragma unroll
    for (int u = 0; u < 8; ++u) {
        float2 r;
        r.x = prelu_(acc[u].x, a1); r.y = prelu_(acc[u].y, a1);
        *(float2*)(x1 + ((b * 64 + o0 + og * 8 + u) << 14) + hw0 + pr * 2) = r;
    }
}

// ---------------- K2: f = relu(conv1x1(x1, wr, br)) ----------------
__global__ __launch_bounds__(256, 4) void k_reduce(const float* __restrict__ x1,
        const float* __restrict__ wr, const float* __restrict__ br,
        float* __restrict__ f) {
    int tid = blockIdx.x * 256 + threadIdx.x;
    int p2 = tid & 16383;            // global px-pair 0..16383
    int q = tid >> 14;               // 0..7, block-uniform
    int b = p2 >> 13;
    int hw = (p2 & 8191) << 1;
    int o0 = q * 4;
    float2 acc[4];
    #pragma unroll
    for (int u = 0; u < 4; ++u) { float bv = br[o0 + u]; acc[u] = make_float2(bv, bv); }
    const float2* xp = (const float2*)(x1 + (b << 20) + hw);  // ch stride 8192 float2
    #pragma unroll 1
    for (int cb = 0; cb < 4; ++cb) {
        float2 xv[16];
        #pragma unroll
        for (int j = 0; j < 16; ++j) xv[j] = xp[(cb * 16 + j) << 13];
        #pragma unroll
        for (int j = 0; j < 16; ++j) {
            int c = cb * 16 + j;
            #pragma unroll
            for (int u = 0; u < 4; ++u) {
                float wv = wr[(o0 + u) * 64 + c];
                acc[u].x = fmaf(wv, xv[j].x, acc[u].x);
                acc[u].y = fmaf(wv, xv[j].y, acc[u].y);
            }
        }
    }
    float2* op = (float2*)(f + (b << 19) + hw);
    #pragma unroll
    for (int u = 0; u < 4; ++u) {
        float2 r;
        r.x = fmaxf(acc[u].x, 0.f); r.y = fmaxf(acc[u].y, 0.f);
        op[(o0 + u) << 13] = r;
    }
}

// ---------------- K_mid: blocks 0..255 = involution ; 256..767 = psec conv3x3 ----
__global__ __launch_bounds__(256) void k_mid(const float* __restrict__ x1,
        const float* __restrict__ f, const float* __restrict__ ws_,
        const float* __restrict__ bs, float* __restrict__ x2,
        float* __restrict__ zp, const float* __restrict__ wp1,
        const float* __restrict__ bp1, const float* __restrict__ app,
        float* __restrict__ p1) {
    __shared__ float smem[14432];          // 57.7 KB shared by both bodies
    if (blockIdx.x < 256) {
        // ---- involution: block = group g x 16x32 px tile; thread = 2 px x 16 ch
        float* tile = smem;                // [16 ch][22 r][41 stride] (2-way alias only)
        int g = blockIdx.x >> 6;           // 0..3
        int t = blockIdx.x & 63;
        int b = t >> 5;
        int tl = t & 31;                   // 8 h-tiles x 4 w-tiles
        int th = tl >> 2, tw = tl & 3;
        int h0 = th * 16, w0 = tw * 32;
        const float* x1g = x1 + ((b * 64 + g * 16) << 14);
        #pragma unroll 1
        for (int rem = threadIdx.x; rem < 836; rem += 256) {   // 22 x 38 halo
            int r = rem / 38, cl = rem - r * 38;
            int hh = h0 + r - 3, ww = w0 + cl - 3;
            bool ok = (hh >= 0 && hh < 128 && ww >= 0 && ww < 128);
            const float* src = x1g + (hh << 7) + ww;
            float v[16];
            #pragma unroll
            for (int c = 0; c < 16; ++c) v[c] = ok ? src[c << 14] : 0.f;
            float* dst = tile + r * 41 + cl;
            #pragma unroll
            for (int c = 0; c < 16; ++c) dst[c * 902] = v[c];
        }
        int lh = threadIdx.x >> 4;         // row 0..15
        int pc = threadIdx.x & 15;         // pair-col 0..15 -> cols 2pc,2pc+1
        int hw = ((h0 + lh) << 7) + w0 + pc * 2;
        float2 fv[32];
        const float* fp = f + (b << 19) + hw;
        #pragma unroll
        for (int c = 0; c < 32; ++c) fv[c] = *(const float2*)&fp[c << 14];
        if (g == 0) {                      // block-uniform: free ZPool
            float2 mx = fv[0], sm = fv[0];
            #pragma unroll
            for (int c = 1; c < 32; ++c) {
                mx.x = fmaxf(mx.x, fv[c].x); mx.y = fmaxf(mx.y, fv[c].y);
                sm.x += fv[c].x; sm.y += fv[c].y;
            }
            *(float2*)&zp[((b * 2 + 0) << 14) + hw] = mx;
            sm.x *= (1.f / 32.f); sm.y *= (1.f / 32.f);
            *(float2*)&zp[((b * 2 + 1) << 14) + hw] = sm;
        }
        __syncthreads();
        float2 acc[16];
        #pragma unroll
        for (int u = 0; u < 16; ++u) acc[u] = make_float2(0.f, 0.f);
        const float* tap0 = tile + lh * 41 + pc * 2;
        const float* wk = ws_ + g * 49 * 32;
        const float* bsg = bs + g * 49;
        #pragma unroll 1
        for (int di = 0; di < 7; ++di) {
            #pragma unroll 1
            for (int dj = 0; dj < 7; ++dj) {
                int kk = di * 7 + dj;
                float bsv = bsg[kk];
                float2 kwv = make_float2(bsv, bsv);
                const float* wkk = wk + kk * 32;
                #pragma unroll
                for (int c = 0; c < 32; ++c) {
                    float wc = wkk[c];
                    kwv.x = fmaf(wc, fv[c].x, kwv.x);
                    kwv.y = fmaf(wc, fv[c].y, kwv.y);
                }
                const float* tp = tap0 + di * 41 + dj;
                #pragma unroll
                for (int u = 0; u < 16; ++u) {
                    float t0 = tp[u * 902], t1 = tp[u * 902 + 1];  // ds_read2
                    acc[u].x = fmaf(kwv.x, t0, acc[u].x);
                    acc[u].y = fmaf(kwv.y, t1, acc[u].y);
                }
            }
        }
        float* op = x2 + ((b * 64 + g * 16) << 14) + hw;
        #pragma unroll
        for (int u = 0; u < 16; ++u) *(float2*)&op[u << 14] = acc[u];
    } else {
        // ---- psec conv3x3: block = 8x16 px tile x 16 outs (2 halves)
        float* fs = smem;                  // 6080 dw: [ci][r(10)][cl(<=18)] stride 19 -> 190/ci
        float* wT = smem + 6080;           // 4608 dw
        int bid = blockIdx.x - 256;        // 0..511
        int half = bid >> 8;
        int t = bid & 255;
        int b = t >> 7;
        int tl = t & 127;                  // 16 h-tiles x 8 w-tiles
        int th = tl >> 3, tw = tl & 7;
        int h0 = th * 8, w0 = tw * 16;
        int o0 = half * 16;
        const float4* wsrc4 = (const float4*)(wp1 + o0 * 288);
        #pragma unroll 1
        for (int e4 = threadIdx.x; e4 < 1152; e4 += 256) {
            float4 v = wsrc4[e4];
            int o = e4 / 72, r4 = (e4 - o * 72) * 4;
            wT[(r4 + 0) * 16 + o] = v.x;
            wT[(r4 + 1) * 16 + o] = v.y;
            wT[(r4 + 2) * 16 + o] = v.z;
            wT[(r4 + 3) * 16 + o] = v.w;
        }
        const float* fb = f + (b << 19);
        #pragma unroll 1
        for (int rem = threadIdx.x; rem < 180; rem += 256) {
            int r = rem / 18, cl = rem - r * 18;
            int hh = h0 + r - 1, ww = w0 + cl - 1;
            bool ok = (hh >= 0 && hh < 128 && ww >= 0 && ww < 128);
            const float* src = fb + (hh << 7) + ww;
            float* dst = fs + r * 19 + cl;
            #pragma unroll 1
            for (int cb = 0; cb < 4; ++cb) {
                float v[8];
                #pragma unroll
                for (int c = 0; c < 8; ++c) v[c] = ok ? src[(cb * 8 + c) << 14] : 0.f;
                #pragma unroll
                for (int c = 0; c < 8; ++c) dst[(cb * 8 + c) * 190] = v[c];
            }
        }
        __syncthreads();
        int pxq = threadIdx.x & 31;
        int rowq = pxq >> 2, colq = pxq & 3;
        int oh = threadIdx.x >> 5;         // 0..7 -> outs o0+oh*2, +1
        const float ap = app[0];
        float acc[2][4];
        #pragma unroll
        for (int o = 0; o < 2; ++o) {
            float bv = bp1[o0 + oh * 2 + o];
            #pragma unroll
            for (int px = 0; px < 4; ++px) acc[o][px] = bv;
        }
        const float* fsb = fs + rowq * 19 + colq * 4;
        for (int ci = 0; ci < 32; ++ci) {
            float tap[3][6];
            const float* base = fsb + ci * 190;
            #pragma unroll
            for (int r = 0; r < 3; ++r)
                #pragma unroll
                for (int j = 0; j < 6; ++j)
                    tap[r][j] = base[r * 19 + j];
            #pragma unroll
            for (int ki = 0; ki < 3; ++ki)
                #pragma unroll
                for (int kj = 0; kj < 3; ++kj) {
                    float2 wv = *(const float2*)&wT[((ci * 9 + ki * 3 + kj) << 4) + oh * 2];
                    #pragma unroll
                    for (int px = 0; px < 4; ++px) {
                        float tv = tap[ki][px + kj];
                        acc[0][px] = fmaf(wv.x, tv, acc[0][px]);
                        acc[1][px] = fmaf(wv.y, tv, acc[1][px]);
                    }
                }
        }
        int hw = ((h0 + rowq) << 7) + w0 + colq * 4;
        #pragma unroll
        for (int o = 0; o < 2; ++o) {
            float4 r;
            r.x = prelu_(acc[o][0], ap); r.y = prelu_(acc[o][1], ap);
            r.z = prelu_(acc[o][2], ap); r.w = prelu_(acc[o][3], ap);
            *(float4*)(p1 + ((b * 32 + o0 + oh * 2 + o) << 14) + hw) = r;
        }
    }
}

// ---------------- K4: attn = sigmoid(conv7x7(zp, wa, ba)) ----------------
__global__ __launch_bounds__(256) void k_attn(const float* __restrict__ zp,
        const float* __restrict__ wa, const float* __restrict__ ba,
        float* __restrict__ attn) {
    __shared__ float zs[2][22 * 23];       // stride 23
    int t = blockIdx.x;                    // 0..127
    int b = t >> 6;
    int tile = t & 63;
    int th = tile >> 3, tw = tile & 7;
    int h0 = th * 16, w0 = tw * 16;
    const float* zb = zp + (b << 15);      // b*2*HW_
    #pragma unroll 1
    for (int rem = threadIdx.x; rem < 484; rem += 256) {
        int r = rem / 22, cl = rem - r * 22;
        int hh = h0 + r - 3, ww = w0 + cl - 3;
        bool ok = (hh >= 0 && hh < 128 && ww >= 0 && ww < 128);
        const float* src = zb + (hh << 7) + ww;
        float v0 = ok ? src[0] : 0.f;
        float v1 = ok ? src[HW_] : 0.f;
        zs[0][r * 23 + cl] = v0;
        zs[1][r * 23 + cl] = v1;
    }
    __syncthreads();
    int lh = threadIdx.x >> 4, lw = threadIdx.x & 15;
    float acc = ba[0];
    #pragma unroll
    for (int c = 0; c < 2; ++c) {
        const float* zc = &zs[c][lh * 23 + lw];
        #pragma unroll
        for (int i = 0; i < 7; ++i)
            #pragma unroll
            for (int j = 0; j < 7; ++j)
                acc = fmaf(wa[c * 49 + i * 7 + j], zc[i * 23 + j], acc);
    }
    attn[(b << 14) + ((h0 + lh) << 7) + w0 + lw] = 1.f / (1.f + expf(-acc));
}

// ---------------- K6: out = conv2(prelu(x2,a2))*attn + (wp2·p1+bp2) --------
// Block = 128 px x 32 outs (4 splits). Thread = 2-px pair x 8 outs, out-group
// wave-uniform -> weight broadcasts.
__global__ __launch_bounds__(256, 2) void k_final(const float* __restrict__ x2,
        const float* __restrict__ p1, const float* __restrict__ attn,
        const float* __restrict__ a2p, const float* __restrict__ w2,
        const float* __restrict__ b2, const float* __restrict__ wp2,
        const float* __restrict__ bp2, float* __restrict__ out) {
    __shared__ float xs2[64 * 128];    // 32 KB prelu(x2)
    __shared__ float ps[32 * 128];     // 16 KB p1
    __shared__ float wT2[64 * 36];     // 9216 B
    __shared__ float wTp[32 * 36];     // 4608 B
    __shared__ float as_[128];         // attn tile
    int split = blockIdx.x >> 8;       // 0..3
    int tile = blockIdx.x & 255;
    int b = tile >> 7;
    int hw0 = (tile & 127) << 7;
    int o0 = split * 32;
    const float a2 = a2p[0];

    for (int e = threadIdx.x; e < 2048; e += 256) {
        int o = e >> 6, c = e & 63;
        wT2[c * 36 + o] = w2[(o0 + o) * 64 + c];
    }
    for (int e = threadIdx.x; e < 1024; e += 256) {
        int o = e >> 5, c = e & 31;
        wTp[c * 36 + o] = wp2[(o0 + o) * 32 + c];
    }
    {
        const float4* xb = (const float4*)(x2 + (b << 20) + hw0);
        float4 xv[8];
        #pragma unroll
        for (int i = 0; i < 8; ++i) {
            int e = threadIdx.x + i * 256;
            xv[i] = xb[((e >> 5) << 12) + (e & 31)];
        }
        #pragma unroll
        for (int i = 0; i < 8; ++i) {
            int e = threadIdx.x + i * 256;
            float4 v = xv[i];
            v.x = prelu_(v.x, a2); v.y = prelu_(v.y, a2);
            v.z = prelu_(v.z, a2); v.w = prelu_(v.w, a2);
            *(float4*)&xs2[(e >> 5) * 128 + (e & 31) * 4] = v;
        }
        const float4* pb = (const float4*)(p1 + (b << 19) + hw0);
        float4 pv[4];
        #pragma unroll
        for (int i = 0; i < 4; ++i) {
            int e = threadIdx.x + i * 256;
            pv[i] = pb[((e >> 5) << 12) + (e & 31)];
        }
        #pragma unroll
        for (int i = 0; i < 4; ++i) {
            int e = threadIdx.x + i * 256;
            *(float4*)&ps[(e >> 5) * 128 + (e & 31) * 4] = pv[i];
        }
        if (threadIdx.x < 32)
            ((float4*)as_)[threadIdx.x] = ((const float4*)(attn + (b << 14) + hw0))[threadIdx.x];
    }
    int pr = threadIdx.x & 63;
    int og = threadIdx.x >> 6;         // wave-uniform
    float b2v[8], bpv[8];
    #pragma unroll
    for (int u = 0; u < 8; ++u) { b2v[u] = b2[o0 + og * 8 + u]; bpv[u] = bp2[o0 + og * 8 + u]; }
    __syncthreads();

    float2 acc[8];
    #pragma unroll
    for (int u = 0; u < 8; ++u) acc[u] = make_float2(0.f, 0.f);
    #pragma unroll 8
    for (int c = 0; c < 64; ++c) {
        float2 tap = *(const float2*)&xs2[c * 128 + pr * 2];
        const float* wb = &wT2[c * 36 + og * 8];
        float4 wva = *(const float4*)wb;
        float4 wvb = *(const float4*)(wb + 4);
        acc[0].x = fmaf(wva.x, tap.x, acc[0].x); acc[0].y = fmaf(wva.x, tap.y, acc[0].y);
        acc[1].x = fmaf(wva.y, tap.x, acc[1].x); acc[1].y = fmaf(wva.y, tap.y, acc[1].y);
        acc[2].x = fmaf(wva.z, tap.x, acc[2].x); acc[2].y = fmaf(wva.z, tap.y, acc[2].y);
        acc[3].x = fmaf(wva.w, tap.x, acc[3].x); acc[3].y = fmaf(wva.w, tap.y, acc[3].y);
        acc[4].x = fmaf(wvb.x, tap.x, acc[4].x); acc[4].y = fmaf(wvb.x, tap.y, acc[4].y);
        acc[5].x = fmaf(wvb.y, tap.x, acc[5].x); acc[5].y = fmaf(wvb.y, tap.y, acc[5].y);
        acc[6].x = fmaf(wvb.z, tap.x, acc[6].x); acc[6].y = fmaf(wvb.z, tap.y, acc[6].y);
        acc[7].x = fmaf(wvb.w, tap.x, acc[7].x); acc[7].y = fmaf(wvb.w, tap.y, acc[7].y);
    }
    float2 at = *(const float2*)&as_[pr * 2];
    #pragma unroll
    for (int u = 0; u < 8; ++u) {
        acc[u].x = (acc[u].x + b2v[u]) * at.x + bpv[u];
        acc[u].y = (acc[u].y + b2v[u]) * at.y + bpv[u];
    }
    #pragma unroll 8
    for (int c = 0; c < 32; ++c) {
        float2 tap = *(const float2*)&ps[c * 128 + pr * 2];
        const float* wb = &wTp[c * 36 + og * 8];
        float4 wva = *(const float4*)wb;
        float4 wvb = *(const float4*)(wb + 4);
        acc[0].x = fmaf(wva.x, tap.x, acc[0].x); acc[0].y = fmaf(wva.x, tap.y, acc[0].y);
        acc[1].x = fmaf(wva.y, tap.x, acc[1].x); acc[1].y = fmaf(wva.y, tap.y, acc[1].y);
        acc[2].x = fmaf(wva.z, tap.x, acc[2].x); acc[2].y = fmaf(wva.z, tap.y, acc[2].y);
        acc[3].x = fmaf(wva.w, tap.x, acc[3].x); acc[3].y = fmaf(wva.w, tap.y, acc[3].y);
        acc[4].x = fmaf(wvb.x, tap.x, acc[4].x); acc[4].y = fmaf(wvb.x, tap.y, acc[4].y);
        acc[5].x = fmaf(wvb.y, tap.x, acc[5].x); acc[5].y = fmaf(wvb.y, tap.y, acc[5].y);
        acc[6].x = fmaf(wvb.z, tap.x, acc[6].x); acc[6].y = fmaf(wvb.z, tap.y, acc[6].y);
        acc[7].x = fmaf(wvb.w, tap.x, acc[7].x); acc[7].y = fmaf(wvb.w, tap.y, acc[7].y);
    }
    #pragma unroll
    for (int u = 0; u < 8; ++u)
        *(float2*)(out + ((b * 128 + o0 + og * 8 + u) << 14) + hw0 + pr * 2) = acc[u];
}

extern "C" void kernel_launch(void* const* d_in, const int* in_sizes, int n_in,
                              void* d_out, int out_size, void* d_ws, size_t ws_size,
                              hipStream_t stream) {
    const float* x   = (const float*)d_in[0];
    const float* w1  = (const float*)d_in[1];
    const float* b1  = (const float*)d_in[2];
    const float* a1  = (const float*)d_in[3];
    const float* wr  = (const float*)d_in[4];
    const float* br  = (const float*)d_in[5];
    const float* ws_ = (const float*)d_in[6];
    const float* bs  = (const float*)d_in[7];
    const float* a2  = (const float*)d_in[8];
    const float* w2  = (const float*)d_in[9];
    const float* b2  = (const float*)d_in[10];
    const float* wa  = (const float*)d_in[11];
    const float* ba  = (const float*)d_in[12];
    const float* wp1 = (const float*)d_in[13];
    const float* bp1 = (const float*)d_in[14];
    const float* ap  = (const float*)d_in[15];
    const float* wp2 = (const float*)d_in[16];
    const float* bp2 = (const float*)d_in[17];
    float* out = (float*)d_out;

    float* w = (float*)d_ws;
    float* ws_x1   = w;                        // 2*64*HW_
    float* ws_f    = ws_x1 + 2 * 64 * HW_;     // 2*32*HW_
    float* ws_x2   = ws_f  + 2 * 32 * HW_;     // 2*64*HW_
    float* ws_zp   = ws_x2 + 2 * 64 * HW_;     // 2*2*HW_
    float* ws_attn = ws_zp + 2 * 2 * HW_;      // NPX
    float* ws_p1   = ws_attn + NPX;            // 2*32*HW_

    hipLaunchKernelGGL(k_conv1, dim3(512), dim3(256), 0, stream,
                       x, w1, b1, a1, ws_x1);
    hipLaunchKernelGGL(k_reduce, dim3(8 * 16384 / 256), dim3(256), 0, stream,
                       ws_x1, wr, br, ws_f);
    hipLaunchKernelGGL(k_mid, dim3(768), dim3(256), 0, stream,
                       ws_x1, ws_f, ws_, bs, ws_x2, ws_zp,
                       wp1, bp1, ap, ws_p1);
    hipLaunchKernelGGL(k_attn, dim3(128), dim3(256), 0, stream,
                       ws_zp, wa, ba, ws_attn);
    hipLaunchKernelGGL(k_final, dim3(1024), dim3(256), 0, stream,
                       ws_x2, ws_p1, ws_attn, a2, w2, b2, wp2, bp2, out);
}

// Round 10
// 182.765 us; speedup vs baseline: 1.0766x; 1.0766x over previous
//
#include <hip/hip_runtime.h>

#define HW_  16384   // H*W = 128*128
#define NPX  32768   // B*H*W

__device__ __forceinline__ float prelu_(float x, float a) { return x >= 0.f ? x : a * x; }

// ---------------- K_front: x1 = prelu(conv1(x)), f = relu(wr·x1), zp = zpool(f) ----
// Block = 64 px, all 64 x1-outs + all 32 f-outs. Thread (GEMM1) = 4 px x 4 outs.
__global__ __launch_bounds__(256, 2) void k_front(const float* __restrict__ x,
        const float* __restrict__ w1, const float* __restrict__ b1,
        const float* __restrict__ a1p, const float* __restrict__ wr,
        const float* __restrict__ br, float* __restrict__ x1,
        float* __restrict__ f, float* __restrict__ zp) {
    __shared__ float sA[12352];        // 49.4 KB, two overlay regions
    float* xs  = sA;                   // 4096: [ch64][px64]
    float* wT1 = sA + 4096;            // 8256: [o64][c] stride 129 (bank 2-way on stage)
    int p0 = blockIdx.x << 6;
    int b = p0 >> 14, hw0 = p0 & 16383;

    for (int e = threadIdx.x; e < 8192; e += 256) {      // coalesced w1, 2-way LDS
        int o = e >> 7, c = e & 127;
        wT1[o * 129 + c] = w1[e];
    }
    int pq = threadIdx.x & 15;         // px-quad 0..15 (4 px)
    int og = threadIdx.x >> 4;         // 0..15 -> outs og*4..+3
    const float a1 = a1p[0];
    float4 acc[4];
    #pragma unroll
    for (int u = 0; u < 4; ++u) { float bv = b1[og * 4 + u]; acc[u] = make_float4(bv, bv, bv, bv); }
    const float* xb = x + (b << 21) + hw0;
    #pragma unroll 1
    for (int half = 0; half < 2; ++half) {
        float4 xv[4];
        #pragma unroll
        for (int i = 0; i < 4; ++i) {
            int e = threadIdx.x + (i << 8);              // ch = e>>4, q = e&15
            xv[i] = *(const float4*)&xb[((half * 64 + (e >> 4)) << 14) + ((e & 15) << 2)];
        }
        __syncthreads();               // prev-iter readers done before restage
        #pragma unroll
        for (int i = 0; i < 4; ++i) {
            int e = threadIdx.x + (i << 8);
            *(float4*)&xs[((e >> 4) << 6) + ((e & 15) << 2)] = xv[i];
        }
        __syncthreads();
        #pragma unroll 4
        for (int c2 = 0; c2 < 64; ++c2) {
            float4 tap = *(const float4*)&xs[(c2 << 6) + (pq << 2)];  // dedup'd b128
            int c = (half << 6) + c2;
            #pragma unroll
            for (int u = 0; u < 4; ++u) {
                float wv = wT1[(og * 4 + u) * 129 + c];  // broadcast b32
                acc[u].x = fmaf(wv, tap.x, acc[u].x);
                acc[u].y = fmaf(wv, tap.y, acc[u].y);
                acc[u].z = fmaf(wv, tap.z, acc[u].z);
                acc[u].w = fmaf(wv, tap.w, acc[u].w);
            }
        }
    }
    float4 res[4];
    #pragma unroll
    for (int u = 0; u < 4; ++u) {
        res[u].x = prelu_(acc[u].x, a1); res[u].y = prelu_(acc[u].y, a1);
        res[u].z = prelu_(acc[u].z, a1); res[u].w = prelu_(acc[u].w, a1);
        *(float4*)(x1 + ((b * 64 + og * 4 + u) << 14) + hw0 + (pq << 2)) = res[u];
    }
    __syncthreads();                   // all xs/wT1 reads done; overlay region 2
    float* x1t = sA;                   // 4352: [c64][px] stride 68 (b128-aligned, 2-way)
    float* wrT = sA + 4352;            // 2080: [fo32][c] stride 65
    float* ft  = sA + 6432;            // 2176: [fo32][px] stride 68
    #pragma unroll
    for (int u = 0; u < 4; ++u)
        *(float4*)&x1t[(og * 4 + u) * 68 + (pq << 2)] = res[u];
    for (int e = threadIdx.x; e < 2048; e += 256) {
        int fo = e >> 6, c = e & 63;
        wrT[fo * 65 + c] = wr[e];
    }
    __syncthreads();
    int pq2 = threadIdx.x & 15;        // px-quad
    int fg = threadIdx.x >> 4;         // 0..15 -> f-outs fg*2, fg*2+1
    float4 fa[2];
    #pragma unroll
    for (int u = 0; u < 2; ++u) { float bv = br[fg * 2 + u]; fa[u] = make_float4(bv, bv, bv, bv); }
    #pragma unroll 4
    for (int c = 0; c < 64; ++c) {
        float4 tap = *(const float4*)&x1t[c * 68 + (pq2 << 2)];
        #pragma unroll
        for (int u = 0; u < 2; ++u) {
            float wv = wrT[(fg * 2 + u) * 65 + c];
            fa[u].x = fmaf(wv, tap.x, fa[u].x);
            fa[u].y = fmaf(wv, tap.y, fa[u].y);
            fa[u].z = fmaf(wv, tap.z, fa[u].z);
            fa[u].w = fmaf(wv, tap.w, fa[u].w);
        }
    }
    #pragma unroll
    for (int u = 0; u < 2; ++u) {
        float4 r;
        r.x = fmaxf(fa[u].x, 0.f); r.y = fmaxf(fa[u].y, 0.f);
        r.z = fmaxf(fa[u].z, 0.f); r.w = fmaxf(fa[u].w, 0.f);
        *(float4*)(f + ((b * 32 + fg * 2 + u) << 14) + hw0 + (pq2 << 2)) = r;
        *(float4*)&ft[(fg * 2 + u) * 68 + (pq2 << 2)] = r;
    }
    __syncthreads();
    if (threadIdx.x < 64) {            // ZPool: 1 px/thread
        int px = threadIdx.x;
        float mx = ft[px], sm = ft[px];
        #pragma unroll
        for (int c = 1; c < 32; ++c) {
            float v = ft[c * 68 + px];
            mx = fmaxf(mx, v); sm += v;
        }
        zp[((b * 2 + 0) << 14) + hw0 + px] = mx;
        zp[((b * 2 + 1) << 14) + hw0 + px] = sm * (1.f / 32.f);
    }
}

// ---------------- K_mid2: [0,512) invol ; [512,1024) psec3x3 ; [1024,1152) attn ----
__global__ __launch_bounds__(256) void k_mid2(const float* __restrict__ x1,
        const float* __restrict__ f, const float* __restrict__ ws_,
        const float* __restrict__ bs, float* __restrict__ x2,
        const float* __restrict__ zp, const float* __restrict__ wp1,
        const float* __restrict__ bp1, const float* __restrict__ app,
        float* __restrict__ p1, const float* __restrict__ wa,
        const float* __restrict__ ba, float* __restrict__ attn) {
    __shared__ float smem[10688];          // 42.75 KB union
    if (blockIdx.x < 512) {
        // ---- involution (round-8 geometry): group g x 16x16 tile
        float* tile = smem;                // [16c][22r][24] rowstride 24
        int g = blockIdx.x >> 7;           // 0..3
        int t = blockIdx.x & 127;
        int b = t >> 6;
        int th = (t >> 3) & 7, tw = t & 7;
        int h0 = th * 16, w0 = tw * 16;
        const float* x1g = x1 + ((b * 64 + g * 16) << 14);
        #pragma unroll 1
        for (int rem = threadIdx.x; rem < 484; rem += 256) {
            int r = rem / 22, cl = rem - r * 22;
            int hh = h0 + r - 3, ww = w0 + cl - 3;
            bool ok = (hh >= 0 && hh < 128 && ww >= 0 && ww < 128);
            const float* src = x1g + (hh << 7) + ww;
            float v[16];
            #pragma unroll
            for (int c = 0; c < 16; ++c) v[c] = ok ? src[c << 14] : 0.f;
            float* dst = tile + r * 24 + cl;
            #pragma unroll
            for (int c = 0; c < 16; ++c) dst[c * 528] = v[c];
        }
        int lh = threadIdx.x >> 4, lw = threadIdx.x & 15;
        int hw = ((h0 + lh) << 7) + w0 + lw;
        float fv[32];
        const float* fp = f + (b << 19) + hw;
        #pragma unroll
        for (int c = 0; c < 32; ++c) fv[c] = fp[c << 14];
        __syncthreads();
        float acc[16];
        #pragma unroll
        for (int u = 0; u < 16; ++u) acc[u] = 0.f;
        const float* tap0 = tile + lh * 24 + lw;
        const float* wk = ws_ + g * 49 * 32;
        const float* bsg = bs + g * 49;
        #pragma unroll 1
        for (int di = 0; di < 7; ++di) {
            #pragma unroll 1
            for (int dj = 0; dj < 7; ++dj) {
                int kk = di * 7 + dj;
                float kwv = bsg[kk];
                const float* wkk = wk + kk * 32;
                #pragma unroll
                for (int c = 0; c < 32; ++c) kwv = fmaf(wkk[c], fv[c], kwv);
                const float* tp = tap0 + di * 24 + dj;
                #pragma unroll
                for (int u = 0; u < 16; ++u)
                    acc[u] = fmaf(kwv, tp[u * 528], acc[u]);
            }
        }
        float* op = x2 + ((b * 64 + g * 16) << 14) + hw;
        #pragma unroll
        for (int u = 0; u < 16; ++u) op[u << 14] = acc[u];
    } else if (blockIdx.x < 1024) {
        // ---- psec conv3x3: 8x16 px tile x 16 outs (2 halves)
        float* fs = smem;                  // 6080: [ci][r(10)][cl] stride 19 -> 190/ci
        float* wT = smem + 6080;           // 4608
        int bid = blockIdx.x - 512;
        int half = bid >> 8;
        int t = bid & 255;
        int b = t >> 7;
        int tl = t & 127;
        int th = tl >> 3, tw = tl & 7;
        int h0 = th * 8, w0 = tw * 16;
        int o0 = half * 16;
        const float4* wsrc4 = (const float4*)(wp1 + o0 * 288);
        #pragma unroll 1
        for (int e4 = threadIdx.x; e4 < 1152; e4 += 256) {
            float4 v = wsrc4[e4];
            int o = e4 / 72, r4 = (e4 - o * 72) * 4;
            wT[(r4 + 0) * 16 + o] = v.x;
            wT[(r4 + 1) * 16 + o] = v.y;
            wT[(r4 + 2) * 16 + o] = v.z;
            wT[(r4 + 3) * 16 + o] = v.w;
        }
        const float* fb = f + (b << 19);
        #pragma unroll 1
        for (int rem = threadIdx.x; rem < 180; rem += 256) {
            int r = rem / 18, cl = rem - r * 18;
            int hh = h0 + r - 1, ww = w0 + cl - 1;
            bool ok = (hh >= 0 && hh < 128 && ww >= 0 && ww < 128);
            const float* src = fb + (hh << 7) + ww;
            float* dst = fs + r * 19 + cl;
            #pragma unroll 1
            for (int cb = 0; cb < 4; ++cb) {
                float v[8];
                #pragma unroll
                for (int c = 0; c < 8; ++c) v[c] = ok ? src[(cb * 8 + c) << 14] : 0.f;
                #pragma unroll
                for (int c = 0; c < 8; ++c) dst[(cb * 8 + c) * 190] = v[c];
            }
        }
        __syncthreads();
        int pxq = threadIdx.x & 31;
        int rowq = pxq >> 2, colq = pxq & 3;
        int oh = threadIdx.x >> 5;         // 0..7 -> outs o0+oh*2, +1
        const float ap = app[0];
        float acc[2][4];
        #pragma unroll
        for (int o = 0; o < 2; ++o) {
            float bv = bp1[o0 + oh * 2 + o];
            #pragma unroll
            for (int px = 0; px < 4; ++px) acc[o][px] = bv;
        }
        const float* fsb = fs + rowq * 19 + colq * 4;
        for (int ci = 0; ci < 32; ++ci) {
            float tap[3][6];
            const float* base = fsb + ci * 190;
            #pragma unroll
            for (int r = 0; r < 3; ++r)
                #pragma unroll
                for (int j = 0; j < 6; ++j)
                    tap[r][j] = base[r * 19 + j];
            #pragma unroll
            for (int ki = 0; ki < 3; ++ki)
                #pragma unroll
                for (int kj = 0; kj < 3; ++kj) {
                    float2 wv = *(const float2*)&wT[((ci * 9 + ki * 3 + kj) << 4) + oh * 2];
                    #pragma unroll
                    for (int px = 0; px < 4; ++px) {
                        float tv = tap[ki][px + kj];
                        acc[0][px] = fmaf(wv.x, tv, acc[0][px]);
                        acc[1][px] = fmaf(wv.y, tv, acc[1][px]);
                    }
                }
        }
        int hw = ((h0 + rowq) << 7) + w0 + colq * 4;
        #pragma unroll
        for (int o = 0; o < 2; ++o) {
            float4 r;
            r.x = prelu_(acc[o][0], ap); r.y = prelu_(acc[o][1], ap);
            r.z = prelu_(acc[o][2], ap); r.w = prelu_(acc[o][3], ap);
            *(float4*)(p1 + ((b * 32 + o0 + oh * 2 + o) << 14) + hw) = r;
        }
    } else {
        // ---- attn: 16x16 tile, zp halo in LDS
        float* zs = smem;                  // 2 x 506, stride 23
        int t = blockIdx.x - 1024;         // 0..127
        int b = t >> 6;
        int tile = t & 63;
        int th = tile >> 3, tw = tile & 7;
        int h0 = th * 16, w0 = tw * 16;
        const float* zb = zp + (b << 15);
        #pragma unroll 1
        for (int rem = threadIdx.x; rem < 484; rem += 256) {
            int r = rem / 22, cl = rem - r * 22;
            int hh = h0 + r - 3, ww = w0 + cl - 3;
            bool ok = (hh >= 0 && hh < 128 && ww >= 0 && ww < 128);
            const float* src = zb + (hh << 7) + ww;
            float v0 = ok ? src[0] : 0.f;
            float v1 = ok ? src[HW_] : 0.f;
            zs[r * 23 + cl] = v0;
            zs[506 + r * 23 + cl] = v1;
        }
        __syncthreads();
        int lh = threadIdx.x >> 4, lw = threadIdx.x & 15;
        float acc = ba[0];
        #pragma unroll
        for (int c = 0; c < 2; ++c) {
            const float* zc = &zs[c * 506 + lh * 23 + lw];
            #pragma unroll
            for (int i = 0; i < 7; ++i)
                #pragma unroll
                for (int j = 0; j < 7; ++j)
                    acc = fmaf(wa[c * 49 + i * 7 + j], zc[i * 23 + j], acc);
        }
        attn[(b << 14) + ((h0 + lh) << 7) + w0 + lw] = 1.f / (1.f + expf(-acc));
    }
}

// ---------------- K_final: out = conv2(prelu(x2,a2))*attn + (wp2·p1+bp2) --------
__global__ __launch_bounds__(256, 2) void k_final(const float* __restrict__ x2,
        const float* __restrict__ p1, const float* __restrict__ attn,
        const float* __restrict__ a2p, const float* __restrict__ w2,
        const float* __restrict__ b2, const float* __restrict__ wp2,
        const float* __restrict__ bp2, float* __restrict__ out) {
    __shared__ float xs2[64 * 128];
    __shared__ float ps[32 * 128];
    __shared__ float wT2[64 * 36];
    __shared__ float wTp[32 * 36];
    __shared__ float as_[128];
    int split = blockIdx.x >> 8;       // 0..3
    int tile = blockIdx.x & 255;
    int b = tile >> 7;
    int hw0 = (tile & 127) << 7;
    int o0 = split * 32;
    const float a2 = a2p[0];

    for (int e = threadIdx.x; e < 2048; e += 256) {
        int o = e >> 6, c = e & 63;
        wT2[c * 36 + o] = w2[(o0 + o) * 64 + c];
    }
    for (int e = threadIdx.x; e < 1024; e += 256) {
        int o = e >> 5, c = e & 31;
        wTp[c * 36 + o] = wp2[(o0 + o) * 32 + c];
    }
    {
        const float4* xb = (const float4*)(x2 + (b << 20) + hw0);
        float4 xv[8];
        #pragma unroll
        for (int i = 0; i < 8; ++i) {
            int e = threadIdx.x + i * 256;
            xv[i] = xb[((e >> 5) << 12) + (e & 31)];
        }
        #pragma unroll
        for (int i = 0; i < 8; ++i) {
            int e = threadIdx.x + i * 256;
            float4 v = xv[i];
            v.x = prelu_(v.x, a2); v.y = prelu_(v.y, a2);
            v.z = prelu_(v.z, a2); v.w = prelu_(v.w, a2);
            *(float4*)&xs2[(e >> 5) * 128 + (e & 31) * 4] = v;
        }
        const float4* pb = (const float4*)(p1 + (b << 19) + hw0);
        float4 pv[4];
        #pragma unroll
        for (int i = 0; i < 4; ++i) {
            int e = threadIdx.x + i * 256;
            pv[i] = pb[((e >> 5) << 12) + (e & 31)];
        }
        #pragma unroll
        for (int i = 0; i < 4; ++i) {
            int e = threadIdx.x + i * 256;
            *(float4*)&ps[(e >> 5) * 128 + (e & 31) * 4] = pv[i];
        }
        if (threadIdx.x < 32)
            ((float4*)as_)[threadIdx.x] = ((const float4*)(attn + (b << 14) + hw0))[threadIdx.x];
    }
    int pr = threadIdx.x & 63;
    int og = threadIdx.x >> 6;         // wave-uniform
    float b2v[8], bpv[8];
    #pragma unroll
    for (int u = 0; u < 8; ++u) { b2v[u] = b2[o0 + og * 8 + u]; bpv[u] = bp2[o0 + og * 8 + u]; }
    __syncthreads();

    float2 acc[8];
    #pragma unroll
    for (int u = 0; u < 8; ++u) acc[u] = make_float2(0.f, 0.f);
    #pragma unroll 8
    for (int c = 0; c < 64; ++c) {
        float2 tap = *(const float2*)&xs2[c * 128 + pr * 2];
        const float* wb = &wT2[c * 36 + og * 8];
        float4 wva = *(const float4*)wb;
        float4 wvb = *(const float4*)(wb + 4);
        acc[0].x = fmaf(wva.x, tap.x, acc[0].x); acc[0].y = fmaf(wva.x, tap.y, acc[0].y);
        acc[1].x = fmaf(wva.y, tap.x, acc[1].x); acc[1].y = fmaf(wva.y, tap.y, acc[1].y);
        acc[2].x = fmaf(wva.z, tap.x, acc[2].x); acc[2].y = fmaf(wva.z, tap.y, acc[2].y);
        acc[3].x = fmaf(wva.w, tap.x, acc[3].x); acc[3].y = fmaf(wva.w, tap.y, acc[3].y);
        acc[4].x = fmaf(wvb.x, tap.x, acc[4].x); acc[4].y = fmaf(wvb.x, tap.y, acc[4].y);
        acc[5].x = fmaf(wvb.y, tap.x, acc[5].x); acc[5].y = fmaf(wvb.y, tap.y, acc[5].y);
        acc[6].x = fmaf(wvb.z, tap.x, acc[6].x); acc[6].y = fmaf(wvb.z, tap.y, acc[6].y);
        acc[7].x = fmaf(wvb.w, tap.x, acc[7].x); acc[7].y = fmaf(wvb.w, tap.y, acc[7].y);
    }
    float2 at = *(const float2*)&as_[pr * 2];
    #pragma unroll
    for (int u = 0; u < 8; ++u) {
        acc[u].x = (acc[u].x + b2v[u]) * at.x + bpv[u];
        acc[u].y = (acc[u].y + b2v[u]) * at.y + bpv[u];
    }
    #pragma unroll 8
    for (int c = 0; c < 32; ++c) {
        float2 tap = *(const float2*)&ps[c * 128 + pr * 2];
        const float* wb = &wTp[c * 36 + og * 8];
        float4 wva = *(const float4*)wb;
        float4 wvb = *(const float4*)(wb + 4);
        acc[0].x = fmaf(wva.x, tap.x, acc[0].x); acc[0].y = fmaf(wva.x, tap.y, acc[0].y);
        acc[1].x = fmaf(wva.y, tap.x, acc[1].x); acc[1].y = fmaf(wva.y, tap.y, acc[1].y);
        acc[2].x = fmaf(wva.z, tap.x, acc[2].x); acc[2].y = fmaf(wva.z, tap.y, acc[2].y);
        acc[3].x = fmaf(wva.w, tap.x, acc[3].x); acc[3].y = fmaf(wva.w, tap.y, acc[3].y);
        acc[4].x = fmaf(wvb.x, tap.x, acc[4].x); acc[4].y = fmaf(wvb.x, tap.y, acc[4].y);
        acc[5].x = fmaf(wvb.y, tap.x, acc[5].x); acc[5].y = fmaf(wvb.y, tap.y, acc[5].y);
        acc[6].x = fmaf(wvb.z, tap.x, acc[6].x); acc[6].y = fmaf(wvb.z, tap.y, acc[6].y);
        acc[7].x = fmaf(wvb.w, tap.x, acc[7].x); acc[7].y = fmaf(wvb.w, tap.y, acc[7].y);
    }
    #pragma unroll
    for (int u = 0; u < 8; ++u)
        *(float2*)(out + ((b * 128 + o0 + og * 8 + u) << 14) + hw0 + pr * 2) = acc[u];
}

extern "C" void kernel_launch(void* const* d_in, const int* in_sizes, int n_in,
                              void* d_out, int out_size, void* d_ws, size_t ws_size,
                              hipStream_t stream) {
    const float* x   = (const float*)d_in[0];
    const float* w1  = (const float*)d_in[1];
    const float* b1  = (const float*)d_in[2];
    const float* a1  = (const float*)d_in[3];
    const float* wr  = (const float*)d_in[4];
    const float* br  = (const float*)d_in[5];
    const float* ws_ = (const float*)d_in[6];
    const float* bs  = (const float*)d_in[7];
    const float* a2  = (const float*)d_in[8];
    const float* w2  = (const float*)d_in[9];
    const float* b2  = (const float*)d_in[10];
    const float* wa  = (const float*)d_in[11];
    const float* ba  = (const float*)d_in[12];
    const float* wp1 = (const float*)d_in[13];
    const float* bp1 = (const float*)d_in[14];
    const float* ap  = (const float*)d_in[15];
    const float* wp2 = (const float*)d_in[16];
    const float* bp2 = (const float*)d_in[17];
    float* out = (float*)d_out;

    float* w = (float*)d_ws;
    float* ws_x1   = w;                        // 2*64*HW_
    float* ws_f    = ws_x1 + 2 * 64 * HW_;     // 2*32*HW_
    float* ws_x2   = ws_f  + 2 * 32 * HW_;     // 2*64*HW_
    float* ws_zp   = ws_x2 + 2 * 64 * HW_;     // 2*2*HW_
    float* ws_attn = ws_zp + 2 * 2 * HW_;      // NPX
    float* ws_p1   = ws_attn + NPX;            // 2*32*HW_

    hipLaunchKernelGGL(k_front, dim3(512), dim3(256), 0, stream,
                       x, w1, b1, a1, wr, br, ws_x1, ws_f, ws_zp);
    hipLaunchKernelGGL(k_mid2, dim3(1152), dim3(256), 0, stream,
                       ws_x1, ws_f, ws_, bs, ws_x2, ws_zp,
                       wp1, bp1, ap, ws_p1, wa, ba, ws_attn);
    hipLaunchKernelGGL(k_final, dim3(1024), dim3(256), 0, stream,
                       ws_x2, ws_p1, ws_attn, a2, w2, b2, wp2, bp2, out);
}

// Round 11
// 176.308 us; speedup vs baseline: 1.1160x; 1.0366x over previous
//
#include <hip/hip_runtime.h>

#define HW_  16384   // H*W = 128*128
#define NPX  32768   // B*H*W

__device__ __forceinline__ float prelu_(float x, float a) { return x >= 0.f ? x : a * x; }

// ---------------- K_front: x1 = prelu(conv1(x)), f = relu(wr·x1), zp = zpool(f) ----
// Block = 64 px, all 64 x1-outs + all 32 f-outs. GEMM1 thread = 4 px x 4 outs,
// weights read as b128 along c (4-c groups).
__global__ __launch_bounds__(256, 3) void k_front(const float* __restrict__ x,
        const float* __restrict__ w1, const float* __restrict__ b1,
        const float* __restrict__ a1p, const float* __restrict__ wr,
        const float* __restrict__ br, float* __restrict__ x1,
        float* __restrict__ f, float* __restrict__ zp) {
    __shared__ float sA[12544];        // 50.2 KB, two overlay regions
    float* xs  = sA;                   // 4096: [ch64][px64]
    float* wT1 = sA + 4096;            // 8448: [o64][c] stride 132 (16B-aligned rows)
    int p0 = blockIdx.x << 6;
    int b = p0 >> 14, hw0 = p0 & 16383;

    for (int e = threadIdx.x; e < 8192; e += 256) {      // coalesced w1; LDS writes conflict-free
        int o = e >> 7, c = e & 127;
        wT1[o * 132 + c] = w1[e];
    }
    int pq = threadIdx.x & 15;         // px-quad 0..15 (4 px)
    int og = threadIdx.x >> 4;         // 0..15 -> outs og*4..+3
    const float a1 = a1p[0];
    float4 acc[4];
    #pragma unroll
    for (int u = 0; u < 4; ++u) { float bv = b1[og * 4 + u]; acc[u] = make_float4(bv, bv, bv, bv); }
    const float* xb = x + (b << 21) + hw0;
    #pragma unroll 1
    for (int half = 0; half < 2; ++half) {
        float4 xv[4];
        #pragma unroll
        for (int i = 0; i < 4; ++i) {
            int e = threadIdx.x + (i << 8);              // ch = e>>4, q = e&15
            xv[i] = *(const float4*)&xb[((half * 64 + (e >> 4)) << 14) + ((e & 15) << 2)];
        }
        __syncthreads();               // prev-iter readers done before restage
        #pragma unroll
        for (int i = 0; i < 4; ++i) {
            int e = threadIdx.x + (i << 8);
            *(float4*)&xs[((e >> 4) << 6) + ((e & 15) << 2)] = xv[i];
        }
        __syncthreads();
        #pragma unroll 4
        for (int c4 = 0; c4 < 16; ++c4) {
            float4 taps[4];
            #pragma unroll
            for (int j = 0; j < 4; ++j)
                taps[j] = *(const float4*)&xs[((c4 * 4 + j) << 6) + (pq << 2)];
            #pragma unroll
            for (int u = 0; u < 4; ++u) {
                float4 wv = *(const float4*)&wT1[(og * 4 + u) * 132 + half * 64 + c4 * 4];
                acc[u].x = fmaf(wv.x, taps[0].x, acc[u].x); acc[u].y = fmaf(wv.x, taps[0].y, acc[u].y);
                acc[u].z = fmaf(wv.x, taps[0].z, acc[u].z); acc[u].w = fmaf(wv.x, taps[0].w, acc[u].w);
                acc[u].x = fmaf(wv.y, taps[1].x, acc[u].x); acc[u].y = fmaf(wv.y, taps[1].y, acc[u].y);
                acc[u].z = fmaf(wv.y, taps[1].z, acc[u].z); acc[u].w = fmaf(wv.y, taps[1].w, acc[u].w);
                acc[u].x = fmaf(wv.z, taps[2].x, acc[u].x); acc[u].y = fmaf(wv.z, taps[2].y, acc[u].y);
                acc[u].z = fmaf(wv.z, taps[2].z, acc[u].z); acc[u].w = fmaf(wv.z, taps[2].w, acc[u].w);
                acc[u].x = fmaf(wv.w, taps[3].x, acc[u].x); acc[u].y = fmaf(wv.w, taps[3].y, acc[u].y);
                acc[u].z = fmaf(wv.w, taps[3].z, acc[u].z); acc[u].w = fmaf(wv.w, taps[3].w, acc[u].w);
            }
        }
    }
    float4 res[4];
    #pragma unroll
    for (int u = 0; u < 4; ++u) {
        res[u].x = prelu_(acc[u].x, a1); res[u].y = prelu_(acc[u].y, a1);
        res[u].z = prelu_(acc[u].z, a1); res[u].w = prelu_(acc[u].w, a1);
        *(float4*)(x1 + ((b * 64 + og * 4 + u) << 14) + hw0 + (pq << 2)) = res[u];
    }
    __syncthreads();                   // all xs/wT1 reads done; overlay region 2
    float* x1t = sA;                   // 4352: [c64][px] stride 68 (b128-aligned)
    float* wrT = sA + 4352;            // 2080: [fo32][c] stride 65
    float* ft  = sA + 6432;            // 2176: [fo32][px] stride 68
    #pragma unroll
    for (int u = 0; u < 4; ++u)
        *(float4*)&x1t[(og * 4 + u) * 68 + (pq << 2)] = res[u];
    for (int e = threadIdx.x; e < 2048; e += 256) {
        int fo = e >> 6, c = e & 63;
        wrT[fo * 65 + c] = wr[e];
    }
    __syncthreads();
    int pq2 = threadIdx.x & 15;        // px-quad
    int fg = threadIdx.x >> 4;         // 0..15 -> f-outs fg*2, fg*2+1
    float4 fa[2];
    #pragma unroll
    for (int u = 0; u < 2; ++u) { float bv = br[fg * 2 + u]; fa[u] = make_float4(bv, bv, bv, bv); }
    #pragma unroll 4
    for (int c = 0; c < 64; ++c) {
        float4 tap = *(const float4*)&x1t[c * 68 + (pq2 << 2)];
        #pragma unroll
        for (int u = 0; u < 2; ++u) {
            float wv = wrT[(fg * 2 + u) * 65 + c];
            fa[u].x = fmaf(wv, tap.x, fa[u].x);
            fa[u].y = fmaf(wv, tap.y, fa[u].y);
            fa[u].z = fmaf(wv, tap.z, fa[u].z);
            fa[u].w = fmaf(wv, tap.w, fa[u].w);
        }
    }
    #pragma unroll
    for (int u = 0; u < 2; ++u) {
        float4 r;
        r.x = fmaxf(fa[u].x, 0.f); r.y = fmaxf(fa[u].y, 0.f);
        r.z = fmaxf(fa[u].z, 0.f); r.w = fmaxf(fa[u].w, 0.f);
        *(float4*)(f + ((b * 32 + fg * 2 + u) << 14) + hw0 + (pq2 << 2)) = r;
        *(float4*)&ft[(fg * 2 + u) * 68 + (pq2 << 2)] = r;
    }
    __syncthreads();
    if (threadIdx.x < 64) {            // ZPool: 1 px/thread
        int px = threadIdx.x;
        float mx = ft[px], sm = ft[px];
        #pragma unroll
        for (int c = 1; c < 32; ++c) {
            float v = ft[c * 68 + px];
            mx = fmaxf(mx, v); sm += v;
        }
        zp[((b * 2 + 0) << 14) + hw0 + px] = mx;
        zp[((b * 2 + 1) << 14) + hw0 + px] = sm * (1.f / 32.f);
    }
}

// ---------------- K_mid2: [0,512) invol ; [512,1024) psec3x3 ; [1024,1152) attn ----
// smem union = 33792 B -> 4 blocks/CU.
__global__ __launch_bounds__(256, 4) void k_mid2(const float* __restrict__ x1,
        const float* __restrict__ f, const float* __restrict__ ws_,
        const float* __restrict__ bs, float* __restrict__ x2,
        const float* __restrict__ zp, const float* __restrict__ wp1,
        const float* __restrict__ bp1, const float* __restrict__ app,
        float* __restrict__ p1, const float* __restrict__ wa,
        const float* __restrict__ ba, float* __restrict__ attn) {
    __shared__ float smem[8448];           // 33.8 KB union
    if (blockIdx.x < 512) {
        // ---- involution: group g x 16x16 tile
        float* tile = smem;                // [16c][22r][24] rowstride 24
        int g = blockIdx.x >> 7;           // 0..3
        int t = blockIdx.x & 127;
        int b = t >> 6;
        int th = (t >> 3) & 7, tw = t & 7;
        int h0 = th * 16, w0 = tw * 16;
        const float* x1g = x1 + ((b * 64 + g * 16) << 14);
        #pragma unroll 1
        for (int rem = threadIdx.x; rem < 484; rem += 256) {
            int r = rem / 22, cl = rem - r * 22;
            int hh = h0 + r - 3, ww = w0 + cl - 3;
            bool ok = (hh >= 0 && hh < 128 && ww >= 0 && ww < 128);
            const float* src = x1g + (hh << 7) + ww;
            float v[16];
            #pragma unroll
            for (int c = 0; c < 16; ++c) v[c] = ok ? src[c << 14] : 0.f;
            float* dst = tile + r * 24 + cl;
            #pragma unroll
            for (int c = 0; c < 16; ++c) dst[c * 528] = v[c];
        }
        int lh = threadIdx.x >> 4, lw = threadIdx.x & 15;
        int hw = ((h0 + lh) << 7) + w0 + lw;
        float fv[32];
        const float* fp = f + (b << 19) + hw;
        #pragma unroll
        for (int c = 0; c < 32; ++c) fv[c] = fp[c << 14];
        __syncthreads();
        float acc[16];
        #pragma unroll
        for (int u = 0; u < 16; ++u) acc[u] = 0.f;
        const float* tap0 = tile + lh * 24 + lw;
        const float* wk = ws_ + g * 49 * 32;
        const float* bsg = bs + g * 49;
        #pragma unroll 1
        for (int di = 0; di < 7; ++di) {
            #pragma unroll 1
            for (int dj = 0; dj < 7; ++dj) {
                int kk = di * 7 + dj;
                float kwv = bsg[kk];
                const float* wkk = wk + kk * 32;
                #pragma unroll
                for (int c = 0; c < 32; ++c) kwv = fmaf(wkk[c], fv[c], kwv);
                const float* tp = tap0 + di * 24 + dj;
                #pragma unroll
                for (int u = 0; u < 16; ++u)
                    acc[u] = fmaf(kwv, tp[u * 528], acc[u]);
            }
        }
        float* op = x2 + ((b * 64 + g * 16) << 14) + hw;
        #pragma unroll
        for (int u = 0; u < 16; ++u) op[u << 14] = acc[u];
    } else if (blockIdx.x < 1024) {
        // ---- psec conv3x3: 8x16 px tile x 16 outs (2 halves); weights chunked
        float* fs = smem;                  // 6080: [ci][r(10)][cl] stride 19 -> 190/ci
        float* wT = smem + 6080;           // 2320: [o16][idx144] stride 145 (conflict-free)
        int bid = blockIdx.x - 512;
        int half = bid >> 8;
        int t = bid & 255;
        int b = t >> 7;
        int tl = t & 127;
        int th = tl >> 3, tw = tl & 7;
        int h0 = th * 8, w0 = tw * 16;
        int o0 = half * 16;
        const float* fb = f + (b << 19);
        #pragma unroll 1
        for (int rem = threadIdx.x; rem < 180; rem += 256) {
            int r = rem / 18, cl = rem - r * 18;
            int hh = h0 + r - 1, ww = w0 + cl - 1;
            bool ok = (hh >= 0 && hh < 128 && ww >= 0 && ww < 128);
            const float* src = fb + (hh << 7) + ww;
            float* dst = fs + r * 19 + cl;
            #pragma unroll 1
            for (int cb = 0; cb < 4; ++cb) {
                float v[8];
                #pragma unroll
                for (int c = 0; c < 8; ++c) v[c] = ok ? src[(cb * 8 + c) << 14] : 0.f;
                #pragma unroll
                for (int c = 0; c < 8; ++c) dst[(cb * 8 + c) * 190] = v[c];
            }
        }
        int pxq = threadIdx.x & 31;
        int rowq = pxq >> 2, colq = pxq & 3;
        int oh = threadIdx.x >> 5;         // 0..7 -> outs o0+oh*2, +1
        const float ap = app[0];
        float acc[2][4];
        #pragma unroll
        for (int o = 0; o < 2; ++o) {
            float bv = bp1[o0 + oh * 2 + o];
            #pragma unroll
            for (int px = 0; px < 4; ++px) acc[o][px] = bv;
        }
        const float* fsb = fs + rowq * 19 + colq * 4;
        #pragma unroll 1
        for (int cih = 0; cih < 2; ++cih) {
            __syncthreads();               // fs ready / prev-chunk wT reads done
            #pragma unroll 1
            for (int e = threadIdx.x; e < 2304; e += 256) {   // straight copy, no conflicts
                int o = e / 144, i = e - o * 144;
                wT[o * 145 + i] = wp1[(o0 + o) * 288 + cih * 144 + i];
            }
            __syncthreads();
            #pragma unroll 1
            for (int cl_ = 0; cl_ < 16; ++cl_) {
                int ci = cih * 16 + cl_;
                float tap[3][6];
                const float* base = fsb + ci * 190;
                #pragma unroll
                for (int r = 0; r < 3; ++r)
                    #pragma unroll
                    for (int j = 0; j < 6; ++j)
                        tap[r][j] = base[r * 19 + j];
                #pragma unroll
                for (int ki = 0; ki < 3; ++ki)
                    #pragma unroll
                    for (int kj = 0; kj < 3; ++kj) {
                        int idx = cl_ * 9 + ki * 3 + kj;
                        float w0v = wT[(oh * 2 + 0) * 145 + idx];   // 2-addr broadcast
                        float w1v = wT[(oh * 2 + 1) * 145 + idx];
                        #pragma unroll
                        for (int px = 0; px < 4; ++px) {
                            float tv = tap[ki][px + kj];
                            acc[0][px] = fmaf(w0v, tv, acc[0][px]);
                            acc[1][px] = fmaf(w1v, tv, acc[1][px]);
                        }
                    }
            }
        }
        int hw = ((h0 + rowq) << 7) + w0 + colq * 4;
        #pragma unroll
        for (int o = 0; o < 2; ++o) {
            float4 r;
            r.x = prelu_(acc[o][0], ap); r.y = prelu_(acc[o][1], ap);
            r.z = prelu_(acc[o][2], ap); r.w = prelu_(acc[o][3], ap);
            *(float4*)(p1 + ((b * 32 + o0 + oh * 2 + o) << 14) + hw) = r;
        }
    } else {
        // ---- attn: 16x16 tile, zp halo in LDS
        float* zs = smem;                  // 2 x 506, stride 23
        int t = blockIdx.x - 1024;         // 0..127
        int b = t >> 6;
        int tile = t & 63;
        int th = tile >> 3, tw = tile & 7;
        int h0 = th * 16, w0 = tw * 16;
        const float* zb = zp + (b << 15);
        #pragma unroll 1
        for (int rem = threadIdx.x; rem < 484; rem += 256) {
            int r = rem / 22, cl = rem - r * 22;
            int hh = h0 + r - 3, ww = w0 + cl - 3;
            bool ok = (hh >= 0 && hh < 128 && ww >= 0 && ww < 128);
            const float* src = zb + (hh << 7) + ww;
            float v0 = ok ? src[0] : 0.f;
            float v1 = ok ? src[HW_] : 0.f;
            zs[r * 23 + cl] = v0;
            zs[506 + r * 23 + cl] = v1;
        }
        __syncthreads();
        int lh = threadIdx.x >> 4, lw = threadIdx.x & 15;
        float acc = ba[0];
        #pragma unroll
        for (int c = 0; c < 2; ++c) {
            const float* zc = &zs[c * 506 + lh * 23 + lw];
            #pragma unroll
            for (int i = 0; i < 7; ++i)
                #pragma unroll
                for (int j = 0; j < 7; ++j)
                    acc = fmaf(wa[c * 49 + i * 7 + j], zc[i * 23 + j], acc);
        }
        attn[(b << 14) + ((h0 + lh) << 7) + w0 + lw] = 1.f / (1.f + expf(-acc));
    }
}

// ---------------- K_final: out = conv2(prelu(x2,a2))*attn + (wp2·p1+bp2) --------
__global__ __launch_bounds__(256, 2) void k_final(const float* __restrict__ x2,
        const float* __restrict__ p1, const float* __restrict__ attn,
        const float* __restrict__ a2p, const float* __restrict__ w2,
        const float* __restrict__ b2, const float* __restrict__ wp2,
        const float* __restrict__ bp2, float* __restrict__ out) {
    __shared__ float xs2[64 * 128];
    __shared__ float ps[32 * 128];
    __shared__ float wT2[64 * 36];
    __shared__ float wTp[32 * 36];
    __shared__ float as_[128];
    int split = blockIdx.x >> 8;       // 0..3
    int tile = blockIdx.x & 255;
    int b = tile >> 7;
    int hw0 = (tile & 127) << 7;
    int o0 = split * 32;
    const float a2 = a2p[0];

    for (int e = threadIdx.x; e < 2048; e += 256) {
        int o = e >> 6, c = e & 63;
        wT2[c * 36 + o] = w2[(o0 + o) * 64 + c];
    }
    for (int e = threadIdx.x; e < 1024; e += 256) {
        int o = e >> 5, c = e & 31;
        wTp[c * 36 + o] = wp2[(o0 + o) * 32 + c];
    }
    {
        const float4* xb = (const float4*)(x2 + (b << 20) + hw0);
        float4 xv[8];
        #pragma unroll
        for (int i = 0; i < 8; ++i) {
            int e = threadIdx.x + i * 256;
            xv[i] = xb[((e >> 5) << 12) + (e & 31)];
        }
        #pragma unroll
        for (int i = 0; i < 8; ++i) {
            int e = threadIdx.x + i * 256;
            float4 v = xv[i];
            v.x = prelu_(v.x, a2); v.y = prelu_(v.y, a2);
            v.z = prelu_(v.z, a2); v.w = prelu_(v.w, a2);
            *(float4*)&xs2[(e >> 5) * 128 + (e & 31) * 4] = v;
        }
        const float4* pb = (const float4*)(p1 + (b << 19) + hw0);
        float4 pv[4];
        #pragma unroll
        for (int i = 0; i < 4; ++i) {
            int e = threadIdx.x + i * 256;
            pv[i] = pb[((e >> 5) << 12) + (e & 31)];
        }
        #pragma unroll
        for (int i = 0; i < 4; ++i) {
            int e = threadIdx.x + i * 256;
            *(float4*)&ps[(e >> 5) * 128 + (e & 31) * 4] = pv[i];
        }
        if (threadIdx.x < 32)
            ((float4*)as_)[threadIdx.x] = ((const float4*)(attn + (b << 14) + hw0))[threadIdx.x];
    }
    int pr = threadIdx.x & 63;
    int og = threadIdx.x >> 6;         // wave-uniform
    float b2v[8], bpv[8];
    #pragma unroll
    for (int u = 0; u < 8; ++u) { b2v[u] = b2[o0 + og * 8 + u]; bpv[u] = bp2[o0 + og * 8 + u]; }
    __syncthreads();

    float2 acc[8];
    #pragma unroll
    for (int u = 0; u < 8; ++u) acc[u] = make_float2(0.f, 0.f);
    #pragma unroll 8
    for (int c = 0; c < 64; ++c) {
        float2 tap = *(const float2*)&xs2[c * 128 + pr * 2];
        const float* wb = &wT2[c * 36 + og * 8];
        float4 wva = *(const float4*)wb;
        float4 wvb = *(const float4*)(wb + 4);
        acc[0].x = fmaf(wva.x, tap.x, acc[0].x); acc[0].y = fmaf(wva.x, tap.y, acc[0].y);
        acc[1].x = fmaf(wva.y, tap.x, acc[1].x); acc[1].y = fmaf(wva.y, tap.y, acc[1].y);
        acc[2].x = fmaf(wva.z, tap.x, acc[2].x); acc[2].y = fmaf(wva.z, tap.y, acc[2].y);
        acc[3].x = fmaf(wva.w, tap.x, acc[3].x); acc[3].y = fmaf(wva.w, tap.y, acc[3].y);
        acc[4].x = fmaf(wvb.x, tap.x, acc[4].x); acc[4].y = fmaf(wvb.x, tap.y, acc[4].y);
        acc[5].x = fmaf(wvb.y, tap.x, acc[5].x); acc[5].y = fmaf(wvb.y, tap.y, acc[5].y);
        acc[6].x = fmaf(wvb.z, tap.x, acc[6].x); acc[6].y = fmaf(wvb.z, tap.y, acc[6].y);
        acc[7].x = fmaf(wvb.w, tap.x, acc[7].x); acc[7].y = fmaf(wvb.w, tap.y, acc[7].y);
    }
    float2 at = *(const float2*)&as_[pr * 2];
    #pragma unroll
    for (int u = 0; u < 8; ++u) {
        acc[u].x = (acc[u].x + b2v[u]) * at.x + bpv[u];
        acc[u].y = (acc[u].y + b2v[u]) * at.y + bpv[u];
    }
    #pragma unroll 8
    for (int c = 0; c < 32; ++c) {
        float2 tap = *(const float2*)&ps[c * 128 + pr * 2];
        const float* wb = &wTp[c * 36 + og * 8];
        float4 wva = *(const float4*)wb;
        float4 wvb = *(const float4*)(wb + 4);
        acc[0].x = fmaf(wva.x, tap.x, acc[0].x); acc[0].y = fmaf(wva.x, tap.y, acc[0].y);
        acc[1].x = fmaf(wva.y, tap.x, acc[1].x); acc[1].y = fmaf(wva.y, tap.y, acc[1].y);
        acc[2].x = fmaf(wva.z, tap.x, acc[2].x); acc[2].y = fmaf(wva.z, tap.y, acc[2].y);
        acc[3].x = fmaf(wva.w, tap.x, acc[3].x); acc[3].y = fmaf(wva.w, tap.y, acc[3].y);
        acc[4].x = fmaf(wvb.x, tap.x, acc[4].x); acc[4].y = fmaf(wvb.x, tap.y, acc[4].y);
        acc[5].x = fmaf(wvb.y, tap.x, acc[5].x); acc[5].y = fmaf(wvb.y, tap.y, acc[5].y);
        acc[6].x = fmaf(wvb.z, tap.x, acc[6].x); acc[6].y = fmaf(wvb.z, tap.y, acc[6].y);
        acc[7].x = fmaf(wvb.w, tap.x, acc[7].x); acc[7].y = fmaf(wvb.w, tap.y, acc[7].y);
    }
    #pragma unroll
    for (int u = 0; u < 8; ++u)
        *(float2*)(out + ((b * 128 + o0 + og * 8 + u) << 14) + hw0 + pr * 2) = acc[u];
}

extern "C" void kernel_launch(void* const* d_in, const int* in_sizes, int n_in,
                              void* d_out, int out_size, void* d_ws, size_t ws_size,
                              hipStream_t stream) {
    const float* x   = (const float*)d_in[0];
    const float* w1  = (const float*)d_in[1];
    const float* b1  = (const float*)d_in[2];
    const float* a1  = (const float*)d_in[3];
    const float* wr  = (const float*)d_in[4];
    const float* br  = (const float*)d_in[5];
    const float* ws_ = (const float*)d_in[6];
    const float* bs  = (const float*)d_in[7];
    const float* a2  = (const float*)d_in[8];
    const float* w2  = (const float*)d_in[9];
    const float* b2  = (const float*)d_in[10];
    const float* wa  = (const float*)d_in[11];
    const float* ba  = (const float*)d_in[12];
    const float* wp1 = (const float*)d_in[13];
    const float* bp1 = (const float*)d_in[14];
    const float* ap  = (const float*)d_in[15];
    const float* wp2 = (const float*)d_in[16];
    const float* bp2 = (const float*)d_in[17];
    float* out = (float*)d_out;

    float* w = (float*)d_ws;
    float* ws_x1   = w;                        // 2*64*HW_
    float* ws_f    = ws_x1 + 2 * 64 * HW_;     // 2*32*HW_
    float* ws_x2   = ws_f  + 2 * 32 * HW_;     // 2*64*HW_
    float* ws_zp   = ws_x2 + 2 * 64 * HW_;     // 2*2*HW_
    float* ws_attn = ws_zp + 2 * 2 * HW_;      // NPX
    float* ws_p1   = ws_attn + NPX;            // 2*32*HW_

    hipLaunchKernelGGL(k_front, dim3(512), dim3(256), 0, stream,
                       x, w1, b1, a1, wr, br, ws_x1, ws_f, ws_zp);
    hipLaunchKernelGGL(k_mid2, dim3(1152), dim3(256), 0, stream,
                       ws_x1, ws_f, ws_, bs, ws_x2, ws_zp,
                       wp1, bp1, ap, ws_p1, wa, ba, ws_attn);
    hipLaunchKernelGGL(k_final, dim3(1024), dim3(256), 0, stream,
                       ws_x2, ws_p1, ws_attn, a2, w2, b2, wp2, bp2, out);
}

// Round 12
// 173.753 us; speedup vs baseline: 1.1324x; 1.0147x over previous
//
#include <hip/hip_runtime.h>

#define HW_  16384   // H*W = 128*128
#define NPX  32768   // B*H*W

__device__ __forceinline__ float prelu_(float x, float a) { return x >= 0.f ? x : a * x; }

// ---------------- K_front: x1 = prelu(conv1(x)), f = relu(wr·x1), zp = zpool(f) ----
__global__ __launch_bounds__(256, 3) void k_front(const float* __restrict__ x,
        const float* __restrict__ w1, const float* __restrict__ b1,
        const float* __restrict__ a1p, const float* __restrict__ wr,
        const float* __restrict__ br, float* __restrict__ x1,
        float* __restrict__ f, float* __restrict__ zp) {
    __shared__ float sA[12544];        // 50.2 KB, two overlay regions
    float* xs  = sA;                   // 4096: [ch64][px64]
    float* wT1 = sA + 4096;            // 8448: [o64][c] stride 132
    int p0 = blockIdx.x << 6;
    int b = p0 >> 14, hw0 = p0 & 16383;

    for (int e = threadIdx.x; e < 8192; e += 256) {
        int o = e >> 7, c = e & 127;
        wT1[o * 132 + c] = w1[e];
    }
    int pq = threadIdx.x & 15;
    int og = threadIdx.x >> 4;
    const float a1 = a1p[0];
    float4 acc[4];
    #pragma unroll
    for (int u = 0; u < 4; ++u) { float bv = b1[og * 4 + u]; acc[u] = make_float4(bv, bv, bv, bv); }
    const float* xb = x + (b << 21) + hw0;
    #pragma unroll 1
    for (int half = 0; half < 2; ++half) {
        float4 xv[4];
        #pragma unroll
        for (int i = 0; i < 4; ++i) {
            int e = threadIdx.x + (i << 8);
            xv[i] = *(const float4*)&xb[((half * 64 + (e >> 4)) << 14) + ((e & 15) << 2)];
        }
        __syncthreads();
        #pragma unroll
        for (int i = 0; i < 4; ++i) {
            int e = threadIdx.x + (i << 8);
            *(float4*)&xs[((e >> 4) << 6) + ((e & 15) << 2)] = xv[i];
        }
        __syncthreads();
        #pragma unroll 4
        for (int c4 = 0; c4 < 16; ++c4) {
            float4 taps[4];
            #pragma unroll
            for (int j = 0; j < 4; ++j)
                taps[j] = *(const float4*)&xs[((c4 * 4 + j) << 6) + (pq << 2)];
            #pragma unroll
            for (int u = 0; u < 4; ++u) {
                float4 wv = *(const float4*)&wT1[(og * 4 + u) * 132 + half * 64 + c4 * 4];
                acc[u].x = fmaf(wv.x, taps[0].x, acc[u].x); acc[u].y = fmaf(wv.x, taps[0].y, acc[u].y);
                acc[u].z = fmaf(wv.x, taps[0].z, acc[u].z); acc[u].w = fmaf(wv.x, taps[0].w, acc[u].w);
                acc[u].x = fmaf(wv.y, taps[1].x, acc[u].x); acc[u].y = fmaf(wv.y, taps[1].y, acc[u].y);
                acc[u].z = fmaf(wv.y, taps[1].z, acc[u].z); acc[u].w = fmaf(wv.y, taps[1].w, acc[u].w);
                acc[u].x = fmaf(wv.z, taps[2].x, acc[u].x); acc[u].y = fmaf(wv.z, taps[2].y, acc[u].y);
                acc[u].z = fmaf(wv.z, taps[2].z, acc[u].z); acc[u].w = fmaf(wv.z, taps[2].w, acc[u].w);
                acc[u].x = fmaf(wv.w, taps[3].x, acc[u].x); acc[u].y = fmaf(wv.w, taps[3].y, acc[u].y);
                acc[u].z = fmaf(wv.w, taps[3].z, acc[u].z); acc[u].w = fmaf(wv.w, taps[3].w, acc[u].w);
            }
        }
    }
    float4 res[4];
    #pragma unroll
    for (int u = 0; u < 4; ++u) {
        res[u].x = prelu_(acc[u].x, a1); res[u].y = prelu_(acc[u].y, a1);
        res[u].z = prelu_(acc[u].z, a1); res[u].w = prelu_(acc[u].w, a1);
        *(float4*)(x1 + ((b * 64 + og * 4 + u) << 14) + hw0 + (pq << 2)) = res[u];
    }
    __syncthreads();
    float* x1t = sA;                   // 4352: [c64][px] stride 68
    float* wrT = sA + 4352;            // 2080: [fo32][c] stride 65
    float* ft  = sA + 6432;            // 2176: [fo32][px] stride 68
    #pragma unroll
    for (int u = 0; u < 4; ++u)
        *(float4*)&x1t[(og * 4 + u) * 68 + (pq << 2)] = res[u];
    for (int e = threadIdx.x; e < 2048; e += 256) {
        int fo = e >> 6, c = e & 63;
        wrT[fo * 65 + c] = wr[e];
    }
    __syncthreads();
    int pq2 = threadIdx.x & 15;
    int fg = threadIdx.x >> 4;
    float4 fa[2];
    #pragma unroll
    for (int u = 0; u < 2; ++u) { float bv = br[fg * 2 + u]; fa[u] = make_float4(bv, bv, bv, bv); }
    #pragma unroll 4
    for (int c = 0; c < 64; ++c) {
        float4 tap = *(const float4*)&x1t[c * 68 + (pq2 << 2)];
        #pragma unroll
        for (int u = 0; u < 2; ++u) {
            float wv = wrT[(fg * 2 + u) * 65 + c];
            fa[u].x = fmaf(wv, tap.x, fa[u].x);
            fa[u].y = fmaf(wv, tap.y, fa[u].y);
            fa[u].z = fmaf(wv, tap.z, fa[u].z);
            fa[u].w = fmaf(wv, tap.w, fa[u].w);
        }
    }
    #pragma unroll
    for (int u = 0; u < 2; ++u) {
        float4 r;
        r.x = fmaxf(fa[u].x, 0.f); r.y = fmaxf(fa[u].y, 0.f);
        r.z = fmaxf(fa[u].z, 0.f); r.w = fmaxf(fa[u].w, 0.f);
        *(float4*)(f + ((b * 32 + fg * 2 + u) << 14) + hw0 + (pq2 << 2)) = r;
        *(float4*)&ft[(fg * 2 + u) * 68 + (pq2 << 2)] = r;
    }
    __syncthreads();
    if (threadIdx.x < 64) {
        int px = threadIdx.x;
        float mx = ft[px], sm = ft[px];
        #pragma unroll
        for (int c = 1; c < 32; ++c) {
            float v = ft[c * 68 + px];
            mx = fmaxf(mx, v); sm += v;
        }
        zp[((b * 2 + 0) << 14) + hw0 + px] = mx;
        zp[((b * 2 + 1) << 14) + hw0 + px] = sm * (1.f / 32.f);
    }
}

// ---------------- K_mid2: [0,512) invol (writes prelu'd x2) ; [512,1024) psec ; [1024,1152) attn ----
__global__ __launch_bounds__(256, 4) void k_mid2(const float* __restrict__ x1,
        const float* __restrict__ f, const float* __restrict__ ws_,
        const float* __restrict__ bs, float* __restrict__ x2,
        const float* __restrict__ zp, const float* __restrict__ wp1,
        const float* __restrict__ bp1, const float* __restrict__ app,
        float* __restrict__ p1, const float* __restrict__ wa,
        const float* __restrict__ ba, float* __restrict__ attn,
        const float* __restrict__ a2p) {
    __shared__ float smem[8448];           // 33.8 KB union
    if (blockIdx.x < 512) {
        // ---- involution: group g x 16x16 tile; epilogue folds prelu(.,a2)
        float* tile = smem;                // [16c][22r][24]
        int g = blockIdx.x >> 7;
        int t = blockIdx.x & 127;
        int b = t >> 6;
        int th = (t >> 3) & 7, tw = t & 7;
        int h0 = th * 16, w0 = tw * 16;
        const float* x1g = x1 + ((b * 64 + g * 16) << 14);
        #pragma unroll 1
        for (int rem = threadIdx.x; rem < 484; rem += 256) {
            int r = rem / 22, cl = rem - r * 22;
            int hh = h0 + r - 3, ww = w0 + cl - 3;
            bool ok = (hh >= 0 && hh < 128 && ww >= 0 && ww < 128);
            const float* src = x1g + (hh << 7) + ww;
            float v[16];
            #pragma unroll
            for (int c = 0; c < 16; ++c) v[c] = ok ? src[c << 14] : 0.f;
            float* dst = tile + r * 24 + cl;
            #pragma unroll
            for (int c = 0; c < 16; ++c) dst[c * 528] = v[c];
        }
        int lh = threadIdx.x >> 4, lw = threadIdx.x & 15;
        int hw = ((h0 + lh) << 7) + w0 + lw;
        float fv[32];
        const float* fp = f + (b << 19) + hw;
        #pragma unroll
        for (int c = 0; c < 32; ++c) fv[c] = fp[c << 14];
        __syncthreads();
        float acc[16];
        #pragma unroll
        for (int u = 0; u < 16; ++u) acc[u] = 0.f;
        const float* tap0 = tile + lh * 24 + lw;
        const float* wk = ws_ + g * 49 * 32;
        const float* bsg = bs + g * 49;
        #pragma unroll 1
        for (int di = 0; di < 7; ++di) {
            #pragma unroll 1
            for (int dj = 0; dj < 7; ++dj) {
                int kk = di * 7 + dj;
                float kwv = bsg[kk];
                const float* wkk = wk + kk * 32;
                #pragma unroll
                for (int c = 0; c < 32; ++c) kwv = fmaf(wkk[c], fv[c], kwv);
                const float* tp = tap0 + di * 24 + dj;
                #pragma unroll
                for (int u = 0; u < 16; ++u)
                    acc[u] = fmaf(kwv, tp[u * 528], acc[u]);
            }
        }
        const float a2 = a2p[0];
        float* op = x2 + ((b * 64 + g * 16) << 14) + hw;
        #pragma unroll
        for (int u = 0; u < 16; ++u) op[u << 14] = prelu_(acc[u], a2);
    } else if (blockIdx.x < 1024) {
        // ---- psec conv3x3
        float* fs = smem;                  // 6080
        float* wT = smem + 6080;           // 2320: [o16][idx144] stride 145
        int bid = blockIdx.x - 512;
        int half = bid >> 8;
        int t = bid & 255;
        int b = t >> 7;
        int tl = t & 127;
        int th = tl >> 3, tw = tl & 7;
        int h0 = th * 8, w0 = tw * 16;
        int o0 = half * 16;
        const float* fb = f + (b << 19);
        #pragma unroll 1
        for (int rem = threadIdx.x; rem < 180; rem += 256) {
            int r = rem / 18, cl = rem - r * 18;
            int hh = h0 + r - 1, ww = w0 + cl - 1;
            bool ok = (hh >= 0 && hh < 128 && ww >= 0 && ww < 128);
            const float* src = fb + (hh << 7) + ww;
            float* dst = fs + r * 19 + cl;
            #pragma unroll 1
            for (int cb = 0; cb < 4; ++cb) {
                float v[8];
                #pragma unroll
                for (int c = 0; c < 8; ++c) v[c] = ok ? src[(cb * 8 + c) << 14] : 0.f;
                #pragma unroll
                for (int c = 0; c < 8; ++c) dst[(cb * 8 + c) * 190] = v[c];
            }
        }
        int pxq = threadIdx.x & 31;
        int rowq = pxq >> 2, colq = pxq & 3;
        int oh = threadIdx.x >> 5;
        const float ap = app[0];
        float acc[2][4];
        #pragma unroll
        for (int o = 0; o < 2; ++o) {
            float bv = bp1[o0 + oh * 2 + o];
            #pragma unroll
            for (int px = 0; px < 4; ++px) acc[o][px] = bv;
        }
        const float* fsb = fs + rowq * 19 + colq * 4;
        #pragma unroll 1
        for (int cih = 0; cih < 2; ++cih) {
            __syncthreads();
            #pragma unroll 1
            for (int e = threadIdx.x; e < 2304; e += 256) {
                int o = e / 144, i = e - o * 144;
                wT[o * 145 + i] = wp1[(o0 + o) * 288 + cih * 144 + i];
            }
            __syncthreads();
            #pragma unroll 1
            for (int cl_ = 0; cl_ < 16; ++cl_) {
                int ci = cih * 16 + cl_;
                float tap[3][6];
                const float* base = fsb + ci * 190;
                #pragma unroll
                for (int r = 0; r < 3; ++r)
                    #pragma unroll
                    for (int j = 0; j < 6; ++j)
                        tap[r][j] = base[r * 19 + j];
                #pragma unroll
                for (int ki = 0; ki < 3; ++ki)
                    #pragma unroll
                    for (int kj = 0; kj < 3; ++kj) {
                        int idx = cl_ * 9 + ki * 3 + kj;
                        float w0v = wT[(oh * 2 + 0) * 145 + idx];
                        float w1v = wT[(oh * 2 + 1) * 145 + idx];
                        #pragma unroll
                        for (int px = 0; px < 4; ++px) {
                            float tv = tap[ki][px + kj];
                            acc[0][px] = fmaf(w0v, tv, acc[0][px]);
                            acc[1][px] = fmaf(w1v, tv, acc[1][px]);
                        }
                    }
            }
        }
        int hw = ((h0 + rowq) << 7) + w0 + colq * 4;
        #pragma unroll
        for (int o = 0; o < 2; ++o) {
            float4 r;
            r.x = prelu_(acc[o][0], ap); r.y = prelu_(acc[o][1], ap);
            r.z = prelu_(acc[o][2], ap); r.w = prelu_(acc[o][3], ap);
            *(float4*)(p1 + ((b * 32 + o0 + oh * 2 + o) << 14) + hw) = r;
        }
    } else {
        // ---- attn
        float* zs = smem;
        int t = blockIdx.x - 1024;
        int b = t >> 6;
        int tile = t & 63;
        int th = tile >> 3, tw = tile & 7;
        int h0 = th * 16, w0 = tw * 16;
        const float* zb = zp + (b << 15);
        #pragma unroll 1
        for (int rem = threadIdx.x; rem < 484; rem += 256) {
            int r = rem / 22, cl = rem - r * 22;
            int hh = h0 + r - 3, ww = w0 + cl - 3;
            bool ok = (hh >= 0 && hh < 128 && ww >= 0 && ww < 128);
            const float* src = zb + (hh << 7) + ww;
            float v0 = ok ? src[0] : 0.f;
            float v1 = ok ? src[HW_] : 0.f;
            zs[r * 23 + cl] = v0;
            zs[506 + r * 23 + cl] = v1;
        }
        __syncthreads();
        int lh = threadIdx.x >> 4, lw = threadIdx.x & 15;
        float acc = ba[0];
        #pragma unroll
        for (int c = 0; c < 2; ++c) {
            const float* zc = &zs[c * 506 + lh * 23 + lw];
            #pragma unroll
            for (int i = 0; i < 7; ++i)
                #pragma unroll
                for (int j = 0; j < 7; ++j)
                    acc = fmaf(wa[c * 49 + i * 7 + j], zc[i * 23 + j], acc);
        }
        attn[(b << 14) + ((h0 + lh) << 7) + w0 + lw] = 1.f / (1.f + expf(-acc));
    }
}

// ---------------- K_final v2: global-streaming. out = conv2(x2p)*attn + wp2·p1 + ... ----
// 8 out-splits x 128 tiles of 256 px = 1024 blocks (4/CU, 16 waves/CU).
// Thread = 4 px x 4 outs; out-group = wave id -> LDS weight reads are
// single-address b128 broadcasts; taps stream from L2 in 8-deep b128 batches.
__global__ __launch_bounds__(256, 4) void k_final(const float* __restrict__ x2p,
        const float* __restrict__ p1, const float* __restrict__ attn,
        const float* __restrict__ w2, const float* __restrict__ b2,
        const float* __restrict__ wp2, const float* __restrict__ bp2,
        float* __restrict__ out) {
    __shared__ float wT2[64 * 20];     // [c][o] stride 20 (b128-aligned)
    __shared__ float wTp[32 * 20];
    int split = blockIdx.x >> 7;       // 0..7, block-uniform
    int tile = blockIdx.x & 127;       // 256-px tiles
    int p0 = tile << 8;
    int b = p0 >> 14, hw0 = p0 & 16383;
    int o0 = split * 16;

    for (int e = threadIdx.x; e < 1024; e += 256) {
        int o = e & 15, c = e >> 4;
        wT2[c * 20 + o] = w2[(o0 + o) * 64 + c];
    }
    for (int e = threadIdx.x; e < 512; e += 256) {
        int o = e & 15, c = e >> 4;
        wTp[c * 20 + o] = wp2[(o0 + o) * 32 + c];
    }
    int q4 = threadIdx.x & 63;         // px-quad 0..63 (256 px)
    int og = threadIdx.x >> 6;         // 0..3, wave-uniform -> outs o0+og*4..+3
    float b2v[4], bpv[4];
    #pragma unroll
    for (int u = 0; u < 4; ++u) { b2v[u] = b2[o0 + og * 4 + u]; bpv[u] = bp2[o0 + og * 4 + u]; }
    float4 acc[4];
    #pragma unroll
    for (int u = 0; u < 4; ++u) acc[u] = make_float4(0.f, 0.f, 0.f, 0.f);
    __syncthreads();

    const float* xb = x2p + (b << 20) + hw0 + (q4 << 2);   // ch stride HW_
    #pragma unroll 1
    for (int cb = 0; cb < 8; ++cb) {
        float4 xv[8];
        #pragma unroll
        for (int j = 0; j < 8; ++j) xv[j] = *(const float4*)&xb[(cb * 8 + j) << 14];
        #pragma unroll
        for (int j = 0; j < 8; ++j) {
            float4 wv = *(const float4*)&wT2[(cb * 8 + j) * 20 + og * 4];  // broadcast
            acc[0].x = fmaf(wv.x, xv[j].x, acc[0].x); acc[0].y = fmaf(wv.x, xv[j].y, acc[0].y);
            acc[0].z = fmaf(wv.x, xv[j].z, acc[0].z); acc[0].w = fmaf(wv.x, xv[j].w, acc[0].w);
            acc[1].x = fmaf(wv.y, xv[j].x, acc[1].x); acc[1].y = fmaf(wv.y, xv[j].y, acc[1].y);
            acc[1].z = fmaf(wv.y, xv[j].z, acc[1].z); acc[1].w = fmaf(wv.y, xv[j].w, acc[1].w);
            acc[2].x = fmaf(wv.z, xv[j].x, acc[2].x); acc[2].y = fmaf(wv.z, xv[j].y, acc[2].y);
            acc[2].z = fmaf(wv.z, xv[j].z, acc[2].z); acc[2].w = fmaf(wv.z, xv[j].w, acc[2].w);
            acc[3].x = fmaf(wv.w, xv[j].x, acc[3].x); acc[3].y = fmaf(wv.w, xv[j].y, acc[3].y);
            acc[3].z = fmaf(wv.w, xv[j].z, acc[3].z); acc[3].w = fmaf(wv.w, xv[j].w, acc[3].w);
        }
    }
    float4 at = *(const float4*)(attn + (b << 14) + hw0 + (q4 << 2));
    #pragma unroll
    for (int u = 0; u < 4; ++u) {
        acc[u].x = (acc[u].x + b2v[u]) * at.x + bpv[u];
        acc[u].y = (acc[u].y + b2v[u]) * at.y + bpv[u];
        acc[u].z = (acc[u].z + b2v[u]) * at.z + bpv[u];
        acc[u].w = (acc[u].w + b2v[u]) * at.w + bpv[u];
    }
    const float* pb = p1 + (b << 19) + hw0 + (q4 << 2);
    #pragma unroll 1
    for (int cb = 0; cb < 4; ++cb) {
        float4 pv[8];
        #pragma unroll
        for (int j = 0; j < 8; ++j) pv[j] = *(const float4*)&pb[(cb * 8 + j) << 14];
        #pragma unroll
        for (int j = 0; j < 8; ++j) {
            float4 wv = *(const float4*)&wTp[(cb * 8 + j) * 20 + og * 4];
            acc[0].x = fmaf(wv.x, pv[j].x, acc[0].x); acc[0].y = fmaf(wv.x, pv[j].y, acc[0].y);
            acc[0].z = fmaf(wv.x, pv[j].z, acc[0].z); acc[0].w = fmaf(wv.x, pv[j].w, acc[0].w);
            acc[1].x = fmaf(wv.y, pv[j].x, acc[1].x); acc[1].y = fmaf(wv.y, pv[j].y, acc[1].y);
            acc[1].z = fmaf(wv.y, pv[j].z, acc[1].z); acc[1].w = fmaf(wv.y, pv[j].w, acc[1].w);
            acc[2].x = fmaf(wv.z, pv[j].x, acc[2].x); acc[2].y = fmaf(wv.z, pv[j].y, acc[2].y);
            acc[2].z = fmaf(wv.z, pv[j].z, acc[2].z); acc[2].w = fmaf(wv.z, pv[j].w, acc[2].w);
            acc[3].x = fmaf(wv.w, pv[j].x, acc[3].x); acc[3].y = fmaf(wv.w, pv[j].y, acc[3].y);
            acc[3].z = fmaf(wv.w, pv[j].z, acc[3].z); acc[3].w = fmaf(wv.w, pv[j].w, acc[3].w);
        }
    }
    #pragma unroll
    for (int u = 0; u < 4; ++u)
        *(float4*)(out + ((b * 128 + o0 + og * 4 + u) << 14) + hw0 + (q4 << 2)) = acc[u];
}

extern "C" void kernel_launch(void* const* d_in, const int* in_sizes, int n_in,
                              void* d_out, int out_size, void* d_ws, size_t ws_size,
                              hipStream_t stream) {
    const float* x   = (const float*)d_in[0];
    const float* w1  = (const float*)d_in[1];
    const float* b1  = (const float*)d_in[2];
    const float* a1  = (const float*)d_in[3];
    const float* wr  = (const float*)d_in[4];
    const float* br  = (const float*)d_in[5];
    const float* ws_ = (const float*)d_in[6];
    const float* bs  = (const float*)d_in[7];
    const float* a2  = (const float*)d_in[8];
    const float* w2  = (const float*)d_in[9];
    const float* b2  = (const float*)d_in[10];
    const float* wa  = (const float*)d_in[11];
    const float* ba  = (const float*)d_in[12];
    const float* wp1 = (const float*)d_in[13];
    const float* bp1 = (const float*)d_in[14];
    const float* ap  = (const float*)d_in[15];
    const float* wp2 = (const float*)d_in[16];
    const float* bp2 = (const float*)d_in[17];
    float* out = (float*)d_out;

    float* w = (float*)d_ws;
    float* ws_x1   = w;                        // 2*64*HW_
    float* ws_f    = ws_x1 + 2 * 64 * HW_;     // 2*32*HW_
    float* ws_x2   = ws_f  + 2 * 32 * HW_;     // 2*64*HW_ (holds prelu'd x2)
    float* ws_zp   = ws_x2 + 2 * 64 * HW_;     // 2*2*HW_
    float* ws_attn = ws_zp + 2 * 2 * HW_;      // NPX
    float* ws_p1   = ws_attn + NPX;            // 2*32*HW_

    hipLaunchKernelGGL(k_front, dim3(512), dim3(256), 0, stream,
                       x, w1, b1, a1, wr, br, ws_x1, ws_f, ws_zp);
    hipLaunchKernelGGL(k_mid2, dim3(1152), dim3(256), 0, stream,
                       ws_x1, ws_f, ws_, bs, ws_x2, ws_zp,
                       wp1, bp1, ap, ws_p1, wa, ba, ws_attn, a2);
    hipLaunchKernelGGL(k_final, dim3(1024), dim3(256), 0, stream,
                       ws_x2, ws_p1, ws_attn, w2, b2, wp2, bp2, out);
}